// Round 7
// baseline (171.867 us; speedup 1.0000x reference)
//
#include <hip/hip_runtime.h>

#define DSZ   128
#define DMSK  127
#define D3    (DSZ * DSZ * DSZ)

// ETA = 2*gamma*sqrt(KN*MASS), gamma = a/sqrt(a^2+1), a = -ln(0.7)/pi
#define KN_F   500000.0f
#define ETA_F  159.535258f
#define DT_F   1e-4f

// tile: 32 x 8 x 4 cells, NT=1024 (16 waves). LDS ~73.9 KB -> 2 blocks/CU
// = 32 waves/CU (was 3x49.7KB -> 24 waves/CU). Halo ratio 3456/1024 = 3.375
// (was 4.5). Each 128B output line still owned by exactly one block.
#define TBX   32
#define TBY   8
#define TBZ   4
#define HALO  2
#define RS    37             // padded x-row stride (cells): 36 + 1
#define PS    444            // plane stride = RS * 12 (y-extent 8+4 halo)
#define SLOTS 3552           // PS * 8 (z-extent 4+4 halo)
#define NT    1024           // threads per block (16 waves)
#define NHALO (36 * 12 * 8)  // 3456 real halo cells staged per block
#define RES_S 1032           // res field stride (dwords): 1032 % 32 == 8 -> sub-lanes spread banks

// ---- tiered offset tables (compile-time, padded pitch) ----------------------
// tier A (33 -> 36 w/ self-pads): r2 <= 4 — where real contacts live; always
//   full compute (self-pair contributes exactly zero).
// tier B (48): r2 in {5,6} — contact only at near-extreme jitter (~0.4%/slot);
//   cheap sq-test, execz-skipped tail.
// exc (44): r2 > 6 — occupied pairs can never contact; only matters for the
//   rare cell with |pos|^2 < 4 (empty neighbors at origin). 125-offset cover.
//
// Quadruple bank-decorrelation: the 4 sub-lanes of a particle group issue one
// ds_read_b128 with addresses lc + tab[t*4+sub]. b128 bank-group = addr16B%8;
// residues derive from off%8 (generic in the permuter). Partition each tier
// into quadruples with 4 DISTINCT mod-8 residues -> intra-group conflict-free
// by construction (any permutation is semantically identical).
struct OffTabs { int a[36]; int b[48]; int e[44]; };

constexpr int residue8(int off) { return ((off % 8) + 8) % 8; }

constexpr void permute_groups(const int* src, int n, int* dst) {
    bool used[64] = {};
    for (int g = 0; g < n / 4; ++g) {
        int resmask = 0;
        for (int s = 0; s < 4; ++s) {
            int pick = -1, bestcnt = -1;
            for (int i = 0; i < n; ++i) {
                if (used[i]) continue;
                const int r = residue8(src[i]);
                if (resmask & (1 << r)) continue;
                int cnt = 0;
                for (int j = 0; j < n; ++j)
                    if (!used[j] && residue8(src[j]) == r) ++cnt;
                if (cnt > bestcnt) { bestcnt = cnt; pick = i; }
            }
            if (pick < 0)   // fallback: distinct impossible, take any unused
                for (int i = 0; i < n && pick < 0; ++i) if (!used[i]) pick = i;
            used[pick] = true;
            resmask |= (1 << residue8(src[pick]));
            dst[g * 4 + s] = src[pick];
        }
    }
}

constexpr OffTabs make_tabs() {
    OffTabs t{};
    int ta[36] = {}; int tb[48] = {};
    int na = 0, nb = 0, ne = 0;
    for (int dz = -2; dz <= 2; ++dz)
        for (int dy = -2; dy <= 2; ++dy)
            for (int dx = -2; dx <= 2; ++dx) {
                const int r2 = dz*dz + dy*dy + dx*dx;
                const int off = dz * PS + dy * RS + dx;
                if (r2 <= 4)      ta[na++] = off;
                else if (r2 <= 6) tb[nb++] = off;
                else              t.e[ne++] = off;
            }
    while (na < 36) ta[na++] = 0;   // self-pads: exactly zero force
    permute_groups(ta, 36, t.a);
    permute_groups(tb, 48, t.b);
    return t;
}
__constant__ OffTabs g_tabs = make_tabs();

// ---- bf16 pack/unpack (velocities vy,vz; RNE) -------------------------------
__device__ __forceinline__ unsigned bf16_rne(float f) {
    unsigned u = __float_as_uint(f);
    u += 0x7fffu + ((u >> 16) & 1u);
    return u >> 16;
}
__device__ __forceinline__ unsigned packvv(float vy, float vz) {
    return bf16_rne(vy) | (bf16_rne(vz) << 16);
}
__device__ __forceinline__ float unpk_lo(unsigned w) { return __uint_as_float(w << 16); }
__device__ __forceinline__ float unpk_hi(unsigned w) { return __uint_as_float(w & 0xffff0000u); }

// ---- pair force from preloaded q/w (single-transcendental: rsq) -------------
// rsd = 1/sqrt(sq+1e-20); dist = sq*rsd; rcd == rsd (valid since real contacts
// have dist >= 0.6; self-pair: sq=0 -> dist=0, all force terms * ddx=0 -> 0).
// contact gate on sq<4 (== dist<2, but independent of the rsq result).
__device__ __forceinline__ void pair_qw(
    const float4 q, const unsigned w,
    float px, float py, float pz, float vx, float vy, float vz,
    float& fx, float& fy, float& fz)
{
    const float ddx = px - q.x, ddy = py - q.y, ddz = pz - q.z;
    const float sq  = fmaf(ddx, ddx, fmaf(ddy, ddy, fmaf(ddz, ddz, 1e-20f)));
    const float rsd = __builtin_amdgcn_rsqf(sq);
    const float dist = sq * rsd;
    const float vn = (fmaf(vx - q.w, ddx, fmaf(vy - unpk_lo(w), ddy, (vz - unpk_hi(w)) * ddz))) * rsd;
    float coef = fmaf(KN_F, dist - 2.0f, ETA_F * vn) * rsd;
    coef = (sq < 4.0f) ? coef : 0.0f;
    fx = fmaf(coef, ddx, fx);
    fy = fmaf(coef, ddy, fy);
    fz = fmaf(coef, ddz, fz);
}

__device__ __forceinline__ void pair_full(
    const float4* __restrict__ lsp, const unsigned* __restrict__ lsv, int n,
    float px, float py, float pz, float vx, float vy, float vz,
    float& fx, float& fy, float& fz)
{
    pair_qw(lsp[n], lsv[n], px, py, pz, vx, vy, vz, fx, fy, fz);
}

// tierB probe: test on preloaded position; rare tail reads lsv lazily
__device__ __forceinline__ void pair_test(
    const float4 q, const unsigned* __restrict__ lsv, int nn,
    float px, float py, float pz, float vx, float vy, float vz,
    float& fx, float& fy, float& fz)
{
    const float ddx = px - q.x, ddy = py - q.y, ddz = pz - q.z;
    const float sq = fmaf(ddx, ddx, fmaf(ddy, ddy, fmaf(ddz, ddz, 1e-20f)));
    if (sq < 4.0f) {
        const float rsd = __builtin_amdgcn_rsqf(sq);
        const float dist = sq * rsd;
        const unsigned w = lsv[nn];
        const float vn = (fmaf(vx - q.w, ddx, fmaf(vy - unpk_lo(w), ddy, (vz - unpk_hi(w)) * ddz))) * rsd;
        const float coef = fmaf(KN_F, dist - 2.0f, ETA_F * vn) * rsd;
        fx = fmaf(coef, ddx, fx);
        fy = fmaf(coef, ddy, fy);
        fz = fmaf(coef, ddz, fz);
    }
}

// ---- the kernel -------------------------------------------------------------
__global__ __launch_bounds__(NT) void dem_tile(
    const float* __restrict__ X, const float* __restrict__ Y, const float* __restrict__ Z,
    const float* __restrict__ VX, const float* __restrict__ VY, const float* __restrict__ VZ,
    float* __restrict__ out)
{
    __shared__ float4 lsp[SLOTS];          // x,y,z,vx  f32   56832 B (res overlays later)
    __shared__ unsigned lsv[SLOTS];        // vy,vz bf16-pair 14208 B
    __shared__ unsigned short plist[NT];
    __shared__ int loff[128];              // 36 tierA + 48 tierB + 44 exc
    __shared__ unsigned int pcnt;
    __shared__ int nreloc;
    __shared__ int relocidx[8];
    __shared__ float relocval[8][7];

    const int tid = threadIdx.x;

    // XCD-aware swizzle: xcd = blockIdx%8 picks a 16-cell-thick z-slab;
    // loc walks x (4) fastest, then y (16), then z-within-slab (4).
    const unsigned raw = blockIdx.x;
    const unsigned xcd = raw & 7, loc = raw >> 3;
    const int bx = (int)((loc & 3) * TBX);
    const int by = (int)(((loc >> 2) & 15) * TBY);
    const int bz = (int)((xcd * 4 + (loc >> 6)) * TBZ);

    if (tid == 0) { pcnt = 0; nreloc = 0; }
    if (tid < 36) loff[tid] = g_tabs.a[tid];
    else if (tid < 84) loff[tid] = g_tabs.b[tid - 36];
    else if (tid < 128) loff[tid] = g_tabs.e[tid - 84];

    // ---- staging: one halo cell per thread-iteration --------------------------
    // 6 coalesced scalar loads per cell -> one conflict-free ds_write_b128 (lsp)
    // + one b32 (lsv). Wraps handled uniformly; pad slot (x==36) never touched.
    {
        const int bx2 = bx - HALO, by2 = by - HALO, bz2 = bz - HALO;
        #pragma unroll
        for (int it = 0; it < 4; ++it) {
            const int u = tid + it * NT;
            if (it < 3 || u < NHALO) {
                const int r  = (int)((unsigned)u / 36u);   // row 0..95 (magic-mul)
                const int xl = u - r * 36;                 // 0..35
                const int hz = (int)((unsigned)r / 12u);   // 0..7
                const int hy = r - hz * 12;                // 0..11
                const int gz = (bz2 + hz) & DMSK;
                const int gy = (by2 + hy) & DMSK;
                const int gx = (bx2 + xl) & DMSK;
                const int g  = (gz << 14) | (gy << 7) | gx;
                const int slot = hz * PS + hy * RS + xl;
                lsp[slot] = make_float4(X[g], Y[g], Z[g], VX[g]);
                lsv[slot] = packvv(VY[g], VZ[g]);
            }
        }
    }

    __syncthreads();   // staging done, pcnt/nreloc init visible

    // ---- own cell, compaction -------------------------------------------------
    const int tx = tid & 31, ty = (tid >> 5) & 7, tz = tid >> 8;
    const int lcc = (tz + HALO) * PS + (ty + HALO) * RS + (tx + HALO);
    const float4 qo = lsp[lcc];
    // occupied <=> stored x != 0 (occupied cells have x >= 0.8; empty exact 0)
    const bool occ = (qo.x != 0.0f);

    {
        const unsigned long long bmask = __ballot(occ);
        const int lane = tid & 63;
        const unsigned int prefix = (unsigned int)__popcll(bmask & ((1ull << lane) - 1ull));
        unsigned int base = 0;
        if (lane == 0) base = atomicAdd(&pcnt, (unsigned int)__popcll(bmask));
        base = __shfl(base, 0, 64);
        if (occ) plist[base + prefix] = (unsigned short)tid;
    }

    // NOTE: empty cells need no integration at all — their state is exactly
    // zero (mask factor in the reference zeroes the update; round(0)==0 ->
    // both cell indices invalid -> dump slot). Their outputs are written as
    // zeros in the res phase; relocation INTO them is handled by the fixups.

    __syncthreads();   // plist complete

    // ---- force phase: 4 lanes per particle ------------------------------------
    const int n = (int)pcnt;
    const int grp = tid >> 2, sub = tid & 3;   // grp 0..255
    float fa[4], fb[4];
    int fcell[4] = { -1, -1, -1, -1 };

    // per-sub-lane offsets are particle-invariant: hoist into registers
    int offA[9], offB[12];
    #pragma unroll
    for (int t = 0; t < 9; ++t)  offA[t] = loff[t * 4 + sub];
    #pragma unroll
    for (int t = 0; t < 12; ++t) offB[t] = loff[36 + t * 4 + sub];

    #pragma unroll
    for (int pp = 0; pp < 4; ++pp) {       // compile-time bound -> static fa/fb/fcell
        const int i = pp * 256 + grp;
        if (i >= n) break;
        const int p  = plist[i];
        const int px_ = p & 31, py_ = (p >> 5) & 7, pz_ = p >> 8;
        const int lc = (pz_ + HALO) * PS + (py_ + HALO) * RS + (px_ + HALO);
        const int cpg = ((bz + pz_) * DSZ + (by + py_)) * DSZ + (bx + px_);

        const float4 qc = lsp[lc];
        const unsigned wc = lsv[lc];
        const float px = qc.x, py = qc.y, pz = qc.z;
        const float vx = qc.w, vy = unpk_lo(wc), vz = unpk_hi(wc);
        float fx = 0.f, fy = 0.f, fz = 0.f;

        // tier A: real contacts — full compute; loads hoisted per chunk of 3
        #pragma unroll
        for (int c = 0; c < 3; ++c) {
            const int n0 = lc + offA[c * 3 + 0];
            const int n1 = lc + offA[c * 3 + 1];
            const int n2 = lc + offA[c * 3 + 2];
            const float4  q0 = lsp[n0], q1 = lsp[n1], q2 = lsp[n2];
            const unsigned w0 = lsv[n0], w1 = lsv[n1], w2 = lsv[n2];
            pair_qw(q0, w0, px, py, pz, vx, vy, vz, fx, fy, fz);
            pair_qw(q1, w1, px, py, pz, vx, vy, vz, fx, fy, fz);
            pair_qw(q2, w2, px, py, pz, vx, vy, vz, fx, fy, fz);
        }

        // tier B: contact needs near-extreme jitter — 6-wide position batches;
        // rare tails execz-skipped, lsv read lazy
        #pragma unroll
        for (int c = 0; c < 2; ++c) {
            const int n0 = lc + offB[c * 6 + 0];
            const int n1 = lc + offB[c * 6 + 1];
            const int n2 = lc + offB[c * 6 + 2];
            const int n3 = lc + offB[c * 6 + 3];
            const int n4 = lc + offB[c * 6 + 4];
            const int n5 = lc + offB[c * 6 + 5];
            const float4 q0 = lsp[n0], q1 = lsp[n1], q2 = lsp[n2];
            const float4 q3 = lsp[n3], q4 = lsp[n4], q5 = lsp[n5];
            pair_test(q0, lsv, n0, px, py, pz, vx, vy, vz, fx, fy, fz);
            pair_test(q1, lsv, n1, px, py, pz, vx, vy, vz, fx, fy, fz);
            pair_test(q2, lsv, n2, px, py, pz, vx, vy, vz, fx, fy, fz);
            pair_test(q3, lsv, n3, px, py, pz, vx, vy, vz, fx, fy, fz);
            pair_test(q4, lsv, n4, px, py, pz, vx, vy, vz, fx, fy, fz);
            pair_test(q5, lsv, n5, px, py, pz, vx, vy, vz, fx, fy, fz);
        }

        // empty neighbors sit at the origin: contribute iff |pos|^2 < 4
        // (the (1,1,1)-corner cell) -> run the excluded 44 offsets there.
        const float sqo = px*px + py*py + pz*pz;
        if (sqo < 4.0f) {
            for (int t = sub; t < 44; t += 4)
                pair_full(lsp, lsv, lc + loff[84 + t], px, py, pz, vx, vy, vz, fx, fy, fz);
        }

        fx += __shfl_xor(fx, 1); fy += __shfl_xor(fy, 1); fz += __shfl_xor(fz, 1);
        fx += __shfl_xor(fx, 2); fy += __shfl_xor(fy, 2); fz += __shfl_xor(fz, 2);

        // boundary forces (mask == 1 here)
        const float bl = (px != 0.0f && px < 1.0f)  ? 1.0f : 0.0f;
        const float br = (px > 126.0f)              ? 1.0f : 0.0f;
        const float bb = (py != 0.0f && py < 1.0f)  ? 1.0f : 0.0f;
        const float bt = (py > 126.0f)              ? 1.0f : 0.0f;
        const float bf = (pz != 0.0f && pz < 1.0f)  ? 1.0f : 0.0f;
        const float bk = (pz > 126.0f)              ? 1.0f : 0.0f;
        const float fxb = KN_F * bl * (1.0f - px) - KN_F * br * (px - 126.0f) - ETA_F * vx * (bl + br);
        const float fyb = KN_F * bb * (1.0f - py) - KN_F * bt * (py - 126.0f) - ETA_F * vy * (bb + bt);
        const float fzb = KN_F * bf * (1.0f - pz) - KN_F * bk * (pz - 126.0f) - ETA_F * vz * (bf + bk);

        const float vxn = vx + DT_F * (-fx + fxb);
        const float vyn = vy + DT_F * (-9.8f - fy + fyb);
        const float vzn = vz + DT_F * (-fz + fzb);
        const float xn = px + DT_F * vxn;
        const float yn = py + DT_F * vyn;
        const float zn = pz + DT_F * vzn;

        const int cx0 = (int)rintf(px), cy0 = (int)rintf(py), cz0 = (int)rintf(pz);
        const int cx1 = (int)rintf(xn), cy1 = (int)rintf(yn), cz1 = (int)rintf(zn);
        const int lo = (cx0 && cy0 && cz0) ? ((cz0 * DSZ + cy0) * DSZ + cx0) : D3;
        const int ln = (cx1 && cy1 && cz1) ? ((cz1 * DSZ + cy1) * DSZ + cx1) : D3;

        const bool zeroed = (lo == cpg) && (ln != cpg);
        const float mk = (ln == cpg) ? 1.0f : (zeroed ? 0.0f : 1.0f);
        const float o0 = zeroed ? 0.f : xn,  o1 = zeroed ? 0.f : yn,  o2 = zeroed ? 0.f : zn;
        const float o3 = zeroed ? 0.f : vxn, o4 = zeroed ? 0.f : vyn, o5 = zeroed ? 0.f : vzn;

        fcell[pp] = p;
        fa[pp] = (sub == 0) ? o0 : (sub == 1) ? o1 : (sub == 2) ? o2 : o3;
        fb[pp] = (sub == 0) ? o4 : (sub == 1) ? o5 : mk;

        if (sub == 0) {   // rare relocation: queue direct fixups
            if (lo != cpg && lo < D3) {
                int s = atomicAdd(&nreloc, 1);
                if (s < 8) { relocidx[s] = lo; for (int f = 0; f < 7; ++f) relocval[s][f] = 0.f; }
            }
            if (ln != cpg && ln < D3) {
                int s = atomicAdd(&nreloc, 1);
                if (s < 8) {
                    relocidx[s] = ln;
                    relocval[s][0] = xn;  relocval[s][1] = yn;  relocval[s][2] = zn;
                    relocval[s][3] = vxn; relocval[s][4] = vyn; relocval[s][5] = vzn;
                    relocval[s][6] = 1.f;
                }
            }
        }
    }

    __syncthreads();   // all lsp/lsv force reads complete -> safe to overlay res

    // ---- result staging (res overlays lsp; stride 1032 spreads sub-lane banks) -
    float* res = (float*)lsp;              // res[f*RES_S + cell], 28896 B
    if (!occ) {
        #pragma unroll
        for (int f = 0; f < 7; ++f) res[f * RES_S + tid] = 0.0f;
    }
    #pragma unroll
    for (int pp = 0; pp < 4; ++pp) {
        if (fcell[pp] >= 0) {
            res[sub * RES_S + fcell[pp]] = fa[pp];
            if (sub < 3) res[(sub + 4) * RES_S + fcell[pp]] = fb[pp];
        }
    }

    __syncthreads();   // res complete

    // ---- fully-coalesced writeback: 7 fields x 256 dwordx4 --------------------
    for (int u = tid; u < 1792; u += NT) {
        const int f = u >> 8, j = u & 255;
        const int cell = 4 * j;
        const int wtx = cell & 31, wty = (cell >> 5) & 7, wtz = cell >> 8;
        const float4 v = *(const float4*)(res + f * RES_S + cell);
        *(float4*)(out + f * D3 + ((bz + wtz) * DSZ + (by + wty)) * DSZ + bx + wtx) = v;
    }

    // ---- rare relocation fixups (never triggers at DT=1e-4) -------------------
    __syncthreads();
    const int nr = nreloc < 8 ? nreloc : 8;
    if (tid < nr) {
        const int idx = relocidx[tid];
        #pragma unroll
        for (int f = 0; f < 7; ++f) out[idx + f * D3] = relocval[tid][f];
    }
}

extern "C" void kernel_launch(void* const* d_in, const int* in_sizes, int n_in,
                              void* d_out, int out_size, void* d_ws, size_t ws_size,
                              hipStream_t stream)
{
    const float* X  = (const float*)d_in[0];
    const float* Y  = (const float*)d_in[1];
    const float* Z  = (const float*)d_in[2];
    const float* VX = (const float*)d_in[3];
    const float* VY = (const float*)d_in[4];
    const float* VZ = (const float*)d_in[5];
    float* out = (float*)d_out;

    dem_tile<<<(D3 / (TBX * TBY * TBZ)), NT, 0, stream>>>(X, Y, Z, VX, VY, VZ, out);
}

// Round 9
// 158.115 us; speedup vs baseline: 1.0870x; 1.0870x over previous
//
#include <hip/hip_runtime.h>

#define DSZ   128
#define DMSK  127
#define D3    (DSZ * DSZ * DSZ)

// ETA = 2*gamma*sqrt(KN*MASS), gamma = a/sqrt(a^2+1), a = -ln(0.7)/pi
#define KN_F   500000.0f
#define ETA_F  159.535258f
#define DT_F   1e-4f

// tile: 32 x 4 x 4 cells -> each 128B output line owned by exactly one block
// (geometry settled by measurement: 32x8x4/NT=1024 regressed 67->87us)
#define TBX   32
#define TBY   4
#define TBZ   4
#define HALO  2
#define RS    37             // padded x-row stride (cells): 36 + 1
#define PS    296            // plane stride = RS * 8
#define SLOTS 2368           // PS * 8
#define NT    512            // threads per block (8 waves)
#define NHALO (36 * 8 * 8)   // 2304 real halo cells staged per block
#define RES_S 520            // res field stride (dwords): 520 % 32 == 8 -> sub-lanes spread banks

// ---- tiered offset tables (compile-time, padded pitch) ----------------------
// tier A (33 -> 36 w/ self-pads): r2 <= 4 — where real contacts live; always
//   full compute (self-pair contributes exactly zero).
// tier B (48): r2 in {5,6} — contact only at near-extreme jitter (~0.4%/slot);
//   cheap sq-test, execz-skipped tail.
// exc (44): r2 > 6 — occupied pairs can never contact; only matters for the
//   rare cell with |pos|^2 < 4 (empty neighbors at origin). 125-offset cover.
//
// Quadruple bank-decorrelation: the 4 sub-lanes of a particle group issue one
// ds_read_b128 with addresses lc + tab[t*4+sub]. b128 bank-group = addr16B%8;
// off%8 = (5*dy+dx)%8 (PS%8==0, RS%8==5). Partition each tier into quadruples
// with 4 DISTINCT mod-8 residues -> intra-group conflict-free by construction
// (any permutation is semantically identical; all entries still computed).
struct OffTabs { int a[36]; int b[48]; int e[44]; };

constexpr int residue8(int off) { return ((off % 8) + 8) % 8; }

constexpr void permute_groups(const int* src, int n, int* dst) {
    bool used[64] = {};
    for (int g = 0; g < n / 4; ++g) {
        int resmask = 0;
        for (int s = 0; s < 4; ++s) {
            int pick = -1, bestcnt = -1;
            for (int i = 0; i < n; ++i) {
                if (used[i]) continue;
                const int r = residue8(src[i]);
                if (resmask & (1 << r)) continue;
                int cnt = 0;
                for (int j = 0; j < n; ++j)
                    if (!used[j] && residue8(src[j]) == r) ++cnt;
                if (cnt > bestcnt) { bestcnt = cnt; pick = i; }
            }
            if (pick < 0)   // fallback: distinct impossible, take any unused
                for (int i = 0; i < n && pick < 0; ++i) if (!used[i]) pick = i;
            used[pick] = true;
            resmask |= (1 << residue8(src[pick]));
            dst[g * 4 + s] = src[pick];
        }
    }
}

constexpr OffTabs make_tabs() {
    OffTabs t{};
    int ta[36] = {}; int tb[48] = {};
    int na = 0, nb = 0, ne = 0;
    for (int dz = -2; dz <= 2; ++dz)
        for (int dy = -2; dy <= 2; ++dy)
            for (int dx = -2; dx <= 2; ++dx) {
                const int r2 = dz*dz + dy*dy + dx*dx;
                const int off = dz * PS + dy * RS + dx;
                if (r2 <= 4)      ta[na++] = off;
                else if (r2 <= 6) tb[nb++] = off;
                else              t.e[ne++] = off;
            }
    while (na < 36) ta[na++] = 0;   // self-pads: exactly zero force
    permute_groups(ta, 36, t.a);
    permute_groups(tb, 48, t.b);
    return t;
}
__constant__ OffTabs g_tabs = make_tabs();

// ---- bf16 pack/unpack (velocities vy,vz; RNE) -------------------------------
__device__ __forceinline__ unsigned bf16_rne(float f) {
    unsigned u = __float_as_uint(f);
    u += 0x7fffu + ((u >> 16) & 1u);
    return u >> 16;
}
__device__ __forceinline__ unsigned packvv(float vy, float vz) {
    return bf16_rne(vy) | (bf16_rne(vz) << 16);
}
__device__ __forceinline__ float unpk_lo(unsigned w) { return __uint_as_float(w << 16); }
__device__ __forceinline__ float unpk_hi(unsigned w) { return __uint_as_float(w & 0xffff0000u); }

// ---- pair force from preloaded q/w (single-transcendental: rsq) -------------
// rsd = 1/sqrt(sq+1e-20); dist = sq*rsd; rcd == rsd (valid since real contacts
// have dist >= 0.6; self-pair: sq=0 -> dist=0, all force terms * ddx=0 -> 0).
// contact gate on sq<4 (== dist<2, but independent of the rsq result).
__device__ __forceinline__ void pair_qw(
    const float4 q, const unsigned w,
    float px, float py, float pz, float vx, float vy, float vz,
    float& fx, float& fy, float& fz)
{
    const float ddx = px - q.x, ddy = py - q.y, ddz = pz - q.z;
    const float sq  = fmaf(ddx, ddx, fmaf(ddy, ddy, fmaf(ddz, ddz, 1e-20f)));
    const float rsd = __builtin_amdgcn_rsqf(sq);
    const float dist = sq * rsd;
    const float vn = (fmaf(vx - q.w, ddx, fmaf(vy - unpk_lo(w), ddy, (vz - unpk_hi(w)) * ddz))) * rsd;
    float coef = fmaf(KN_F, dist - 2.0f, ETA_F * vn) * rsd;
    coef = (sq < 4.0f) ? coef : 0.0f;
    fx = fmaf(coef, ddx, fx);
    fy = fmaf(coef, ddy, fy);
    fz = fmaf(coef, ddz, fz);
}

__device__ __forceinline__ void pair_full(
    const float4* __restrict__ lsp, const unsigned* __restrict__ lsv, int n,
    float px, float py, float pz, float vx, float vy, float vz,
    float& fx, float& fy, float& fz)
{
    pair_qw(lsp[n], lsv[n], px, py, pz, vx, vy, vz, fx, fy, fz);
}

// tierB probe: test on preloaded position; rare tail reads lsv lazily
__device__ __forceinline__ void pair_test(
    const float4 q, const unsigned* __restrict__ lsv, int nn,
    float px, float py, float pz, float vx, float vy, float vz,
    float& fx, float& fy, float& fz)
{
    const float ddx = px - q.x, ddy = py - q.y, ddz = pz - q.z;
    const float sq = fmaf(ddx, ddx, fmaf(ddy, ddy, fmaf(ddz, ddz, 1e-20f)));
    if (sq < 4.0f) {
        const float rsd = __builtin_amdgcn_rsqf(sq);
        const float dist = sq * rsd;
        const unsigned w = lsv[nn];
        const float vn = (fmaf(vx - q.w, ddx, fmaf(vy - unpk_lo(w), ddy, (vz - unpk_hi(w)) * ddz))) * rsd;
        const float coef = fmaf(KN_F, dist - 2.0f, ETA_F * vn) * rsd;
        fx = fmaf(coef, ddx, fx);
        fy = fmaf(coef, ddy, fy);
        fz = fmaf(coef, ddz, fz);
    }
}

// ---- the kernel -------------------------------------------------------------
// (NT,4): VGPR cap 128 — verified no-spill at 60 VGPR (r5). The (NT,6) spill
// variant was 61us but is the prime suspect in a fresh-container core dump
// (scratch + graph capture); staying no-spill this round.
__global__ __launch_bounds__(NT, 4) void dem_tile(
    const float* __restrict__ X, const float* __restrict__ Y, const float* __restrict__ Z,
    const float* __restrict__ VX, const float* __restrict__ VY, const float* __restrict__ VZ,
    float* __restrict__ out)
{
    __shared__ float4 lsp[SLOTS];          // x,y,z,vx  f32   37888 B (res overlays later)
    __shared__ unsigned lsv[SLOTS];        // vy,vz bf16-pair  9472 B
    __shared__ unsigned short plist[NT];
    __shared__ int loff[128];              // 36 tierA + 48 tierB + 44 exc
    __shared__ unsigned int pcnt;
    __shared__ int nreloc;
    __shared__ int relocidx[8];
    __shared__ float relocval[8][7];

    const int tid = threadIdx.x;

    // XCD-aware swizzle: xcd = blockIdx%8 picks a 16-cell-thick z-slab;
    // loc walks x (4) fastest, then y (32), then z-within-slab (4).
    const unsigned raw = blockIdx.x;
    const unsigned xcd = raw & 7, loc = raw >> 3;
    const int bx = (int)((loc & 3) * TBX);
    const int by = (int)(((loc >> 2) & 31) * TBY);
    const int bz = (int)((xcd * 4 + (loc >> 7)) * TBZ);

    if (tid == 0) { pcnt = 0; nreloc = 0; }
    if (tid < 36) loff[tid] = g_tabs.a[tid];
    else if (tid < 84) loff[tid] = g_tabs.b[tid - 36];
    else if (tid < 128) loff[tid] = g_tabs.e[tid - 84];

    // ---- staging: one halo cell per thread-iteration --------------------------
    // 6 coalesced scalar loads per cell -> one conflict-free ds_write_b128 (lsp)
    // + one b32 (lsv). Wraps handled uniformly; pad slot (x==36) never touched.
    {
        const int bx2 = bx - HALO, by2 = by - HALO, bz2 = bz - HALO;
        #pragma unroll
        for (int it = 0; it < 5; ++it) {
            const int u = tid + it * NT;
            if (it < 4 || u < NHALO) {
                const int r  = (int)((unsigned)u / 36u);   // row 0..63 (magic-mul)
                const int xl = u - r * 36;                 // 0..35
                const int hz = r >> 3, hy = r & 7;
                const int gz = (bz2 + hz) & DMSK;
                const int gy = (by2 + hy) & DMSK;
                const int gx = (bx2 + xl) & DMSK;
                const int g  = (gz << 14) | (gy << 7) | gx;
                const int slot = hz * PS + hy * RS + xl;
                lsp[slot] = make_float4(X[g], Y[g], Z[g], VX[g]);
                lsv[slot] = packvv(VY[g], VZ[g]);
            }
        }
    }

    __syncthreads();   // staging done, pcnt/nreloc init visible

    // ---- own cell, compaction -------------------------------------------------
    const int tx = tid & 31, ty = (tid >> 5) & 3, tz = tid >> 7;
    const int lcc = (tz + HALO) * PS + (ty + HALO) * RS + (tx + HALO);
    const float4 qo = lsp[lcc];
    // occupied <=> stored x != 0 (occupied cells have x >= 0.8; empty exact 0)
    const bool occ = (qo.x != 0.0f);

    {
        const unsigned long long bmask = __ballot(occ);
        const int lane = tid & 63;
        const unsigned int prefix = (unsigned int)__popcll(bmask & ((1ull << lane) - 1ull));
        unsigned int base = 0;
        if (lane == 0) base = atomicAdd(&pcnt, (unsigned int)__popcll(bmask));
        base = __shfl(base, 0, 64);
        if (occ) plist[base + prefix] = (unsigned short)tid;
    }

    // NOTE: empty cells need no integration at all — their state is exactly
    // zero (mask factor in the reference zeroes the update; round(0)==0 ->
    // both cell indices invalid -> dump slot). Their outputs are written as
    // zeros in the res phase; relocation INTO them is handled by the fixups.

    __syncthreads();   // plist complete

    // ---- force phase: 4 lanes per particle ------------------------------------
    const int n = (int)pcnt;
    const int grp = tid >> 2, sub = tid & 3;
    float fa[4], fb[4];
    int fcell[4] = { -1, -1, -1, -1 };

    // per-sub-lane offsets are particle-invariant: hoist into registers
    int offA[9], offB[12];
    #pragma unroll
    for (int t = 0; t < 9; ++t)  offA[t] = loff[t * 4 + sub];
    #pragma unroll
    for (int t = 0; t < 12; ++t) offB[t] = loff[36 + t * 4 + sub];

    #pragma unroll
    for (int pp = 0; pp < 4; ++pp) {       // compile-time bound -> static fa/fb/fcell
        const int i = pp * 128 + grp;
        if (i >= n) break;
        const int p  = plist[i];
        const int px_ = p & 31, py_ = (p >> 5) & 3, pz_ = p >> 7;
        const int lc = (pz_ + HALO) * PS + (py_ + HALO) * RS + (px_ + HALO);
        const int cpg = ((bz + pz_) * DSZ + (by + py_)) * DSZ + (bx + px_);

        const float4 qc = lsp[lc];
        const unsigned wc = lsv[lc];
        const float px = qc.x, py = qc.y, pz = qc.z;
        const float vx = qc.w, vy = unpk_lo(wc), vz = unpk_hi(wc);

        // TWO independent accumulator triples: tierA -> a-set, tierB/exc ->
        // b-set, summed once before the shuffle reduce. FP non-associativity
        // means the compiler cannot split the 21-deep fmac chain itself; this
        // halves the serial dependence (the untried latency lever).
        float fxa = 0.f, fya = 0.f, fza = 0.f;
        float fxb2 = 0.f, fyb2 = 0.f, fzb2 = 0.f;

        // tier A: real contacts — full compute; loads hoisted per chunk of 3
        #pragma unroll
        for (int c = 0; c < 3; ++c) {
            const int n0 = lc + offA[c * 3 + 0];
            const int n1 = lc + offA[c * 3 + 1];
            const int n2 = lc + offA[c * 3 + 2];
            const float4  q0 = lsp[n0], q1 = lsp[n1], q2 = lsp[n2];
            const unsigned w0 = lsv[n0], w1 = lsv[n1], w2 = lsv[n2];
            pair_qw(q0, w0, px, py, pz, vx, vy, vz, fxa, fya, fza);
            pair_qw(q1, w1, px, py, pz, vx, vy, vz, fxb2, fyb2, fzb2);
            pair_qw(q2, w2, px, py, pz, vx, vy, vz, fxa, fya, fza);
        }

        // tier B: contact needs near-extreme jitter — 6-wide position batches;
        // rare tails execz-skipped, lsv read lazy; alternate accumulator sets
        #pragma unroll
        for (int c = 0; c < 2; ++c) {
            const int n0 = lc + offB[c * 6 + 0];
            const int n1 = lc + offB[c * 6 + 1];
            const int n2 = lc + offB[c * 6 + 2];
            const int n3 = lc + offB[c * 6 + 3];
            const int n4 = lc + offB[c * 6 + 4];
            const int n5 = lc + offB[c * 6 + 5];
            const float4 q0 = lsp[n0], q1 = lsp[n1], q2 = lsp[n2];
            const float4 q3 = lsp[n3], q4 = lsp[n4], q5 = lsp[n5];
            pair_test(q0, lsv, n0, px, py, pz, vx, vy, vz, fxa, fya, fza);
            pair_test(q1, lsv, n1, px, py, pz, vx, vy, vz, fxb2, fyb2, fzb2);
            pair_test(q2, lsv, n2, px, py, pz, vx, vy, vz, fxa, fya, fza);
            pair_test(q3, lsv, n3, px, py, pz, vx, vy, vz, fxb2, fyb2, fzb2);
            pair_test(q4, lsv, n4, px, py, pz, vx, vy, vz, fxa, fya, fza);
            pair_test(q5, lsv, n5, px, py, pz, vx, vy, vz, fxb2, fyb2, fzb2);
        }

        // empty neighbors sit at the origin: contribute iff |pos|^2 < 4
        // (the (1,1,1)-corner cell) -> run the excluded 44 offsets there.
        const float sqo = px*px + py*py + pz*pz;
        if (sqo < 4.0f) {
            for (int t = sub; t < 44; t += 4)
                pair_full(lsp, lsv, lc + loff[84 + t], px, py, pz, vx, vy, vz, fxb2, fyb2, fzb2);
        }

        float fx = fxa + fxb2, fy = fya + fyb2, fz = fza + fzb2;

        fx += __shfl_xor(fx, 1); fy += __shfl_xor(fy, 1); fz += __shfl_xor(fz, 1);
        fx += __shfl_xor(fx, 2); fy += __shfl_xor(fy, 2); fz += __shfl_xor(fz, 2);

        // boundary forces (mask == 1 here)
        const float bl = (px != 0.0f && px < 1.0f)  ? 1.0f : 0.0f;
        const float br = (px > 126.0f)              ? 1.0f : 0.0f;
        const float bb = (py != 0.0f && py < 1.0f)  ? 1.0f : 0.0f;
        const float bt = (py > 126.0f)              ? 1.0f : 0.0f;
        const float bf = (pz != 0.0f && pz < 1.0f)  ? 1.0f : 0.0f;
        const float bk = (pz > 126.0f)              ? 1.0f : 0.0f;
        const float fxb = KN_F * bl * (1.0f - px) - KN_F * br * (px - 126.0f) - ETA_F * vx * (bl + br);
        const float fyb = KN_F * bb * (1.0f - py) - KN_F * bt * (py - 126.0f) - ETA_F * vy * (bb + bt);
        const float fzb = KN_F * bf * (1.0f - pz) - KN_F * bk * (pz - 126.0f) - ETA_F * vz * (bf + bk);

        const float vxn = vx + DT_F * (-fx + fxb);
        const float vyn = vy + DT_F * (-9.8f - fy + fyb);
        const float vzn = vz + DT_F * (-fz + fzb);
        const float xn = px + DT_F * vxn;
        const float yn = py + DT_F * vyn;
        const float zn = pz + DT_F * vzn;

        const int cx0 = (int)rintf(px), cy0 = (int)rintf(py), cz0 = (int)rintf(pz);
        const int cx1 = (int)rintf(xn), cy1 = (int)rintf(yn), cz1 = (int)rintf(zn);
        const int lo = (cx0 && cy0 && cz0) ? ((cz0 * DSZ + cy0) * DSZ + cx0) : D3;
        const int ln = (cx1 && cy1 && cz1) ? ((cz1 * DSZ + cy1) * DSZ + cx1) : D3;

        const bool zeroed = (lo == cpg) && (ln != cpg);
        const float mk = (ln == cpg) ? 1.0f : (zeroed ? 0.0f : 1.0f);
        const float o0 = zeroed ? 0.f : xn,  o1 = zeroed ? 0.f : yn,  o2 = zeroed ? 0.f : zn;
        const float o3 = zeroed ? 0.f : vxn, o4 = zeroed ? 0.f : vyn, o5 = zeroed ? 0.f : vzn;

        fcell[pp] = p;
        fa[pp] = (sub == 0) ? o0 : (sub == 1) ? o1 : (sub == 2) ? o2 : o3;
        fb[pp] = (sub == 0) ? o4 : (sub == 1) ? o5 : mk;

        if (sub == 0) {   // rare relocation: queue direct fixups
            if (lo != cpg && lo < D3) {
                int s = atomicAdd(&nreloc, 1);
                if (s < 8) { relocidx[s] = lo; for (int f = 0; f < 7; ++f) relocval[s][f] = 0.f; }
            }
            if (ln != cpg && ln < D3) {
                int s = atomicAdd(&nreloc, 1);
                if (s < 8) {
                    relocidx[s] = ln;
                    relocval[s][0] = xn;  relocval[s][1] = yn;  relocval[s][2] = zn;
                    relocval[s][3] = vxn; relocval[s][4] = vyn; relocval[s][5] = vzn;
                    relocval[s][6] = 1.f;
                }
            }
        }
    }

    __syncthreads();   // all lsp/lsv force reads complete -> safe to overlay res

    // ---- result staging (res overlays lsp; stride 520 spreads sub-lane banks) --
    float* res = (float*)lsp;              // res[f*RES_S + cell], 14560 B
    if (!occ) {
        #pragma unroll
        for (int f = 0; f < 7; ++f) res[f * RES_S + tid] = 0.0f;
    }
    #pragma unroll
    for (int pp = 0; pp < 4; ++pp) {
        if (fcell[pp] >= 0) {
            res[sub * RES_S + fcell[pp]] = fa[pp];
            if (sub < 3) res[(sub + 4) * RES_S + fcell[pp]] = fb[pp];
        }
    }

    __syncthreads();   // res complete

    // ---- fully-coalesced writeback: 7 fields x 128 dwordx4 --------------------
    for (int u = tid; u < 896; u += NT) {
        const int f = u >> 7, j = u & 127;
        const int cell = 4 * j;
        const int wtx = cell & 31, wty = (cell >> 5) & 3, wtz = cell >> 7;
        const float4 v = *(const float4*)(res + f * RES_S + cell);
        *(float4*)(out + f * D3 + ((bz + wtz) * DSZ + (by + wty)) * DSZ + bx + wtx) = v;
    }

    // ---- rare relocation fixups (never triggers at DT=1e-4) -------------------
    __syncthreads();
    const int nr = nreloc < 8 ? nreloc : 8;
    if (tid < nr) {
        const int idx = relocidx[tid];
        #pragma unroll
        for (int f = 0; f < 7; ++f) out[idx + f * D3] = relocval[tid][f];
    }
}

extern "C" void kernel_launch(void* const* d_in, const int* in_sizes, int n_in,
                              void* d_out, int out_size, void* d_ws, size_t ws_size,
                              hipStream_t stream)
{
    const float* X  = (const float*)d_in[0];
    const float* Y  = (const float*)d_in[1];
    const float* Z  = (const float*)d_in[2];
    const float* VX = (const float*)d_in[3];
    const float* VY = (const float*)d_in[4];
    const float* VZ = (const float*)d_in[5];
    float* out = (float*)d_out;

    dem_tile<<<(D3 / (TBX * TBY * TBZ)), NT, 0, stream>>>(X, Y, Z, VX, VY, VZ, out);
}

// Round 10
// 148.379 us; speedup vs baseline: 1.1583x; 1.0656x over previous
//
#include <hip/hip_runtime.h>

#define DSZ   128
#define DMSK  127
#define D3    (DSZ * DSZ * DSZ)

// ETA = 2*gamma*sqrt(KN*MASS), gamma = a/sqrt(a^2+1), a = -ln(0.7)/pi
#define KN_F   500000.0f
#define ETA_F  159.535258f
#define DT_F   1e-4f

// tile: 32 x 4 x 4 cells -> each 128B output line owned by exactly one block
// (geometry settled by measurement: 32x8x4/NT=1024 regressed 67->87us)
#define TBX   32
#define TBY   4
#define TBZ   4
#define HALO  2
#define RS    37             // padded x-row stride (cells): 36 + 1
#define PS    296            // plane stride = RS * 8
#define SLOTS 2368           // PS * 8
#define NT    512            // threads per block (8 waves)
#define NHALO (36 * 8 * 8)   // 2304 real halo cells staged per block
#define RES_S 520            // res field stride (dwords): 520 % 32 == 8 -> sub-lanes spread banks

// ---- tiered offset tables (compile-time, padded pitch) ----------------------
// tier A (33 -> 36 w/ self-pads): r2 <= 4 — where real contacts live; always
//   full compute (self-pair contributes exactly zero).
// tier B (48): r2 in {5,6} — contact only at near-extreme jitter;
//   cheap sq-test, execz-skipped tail.
// exc (44): r2 > 6 — occupied pairs can never contact; only matters for the
//   rare cell with |pos|^2 < 4 (empty neighbors at origin). 125-offset cover.
//
// Quadruple bank-decorrelation: the 4 sub-lanes of a particle group issue one
// ds_read_b128 with addresses lc + tab[t*4+sub]. b128 bank-group = addr16B%8;
// off%8 = (5*dy+dx)%8 (PS%8==0, RS%8==5). Partition each tier into quadruples
// with 4 DISTINCT mod-8 residues -> intra-group conflict-free by construction
// (any permutation is semantically identical; all entries still computed).
struct OffTabs { int a[36]; int b[48]; int e[44]; };

constexpr int residue8(int off) { return ((off % 8) + 8) % 8; }

constexpr void permute_groups(const int* src, int n, int* dst) {
    bool used[64] = {};
    for (int g = 0; g < n / 4; ++g) {
        int resmask = 0;
        for (int s = 0; s < 4; ++s) {
            int pick = -1, bestcnt = -1;
            for (int i = 0; i < n; ++i) {
                if (used[i]) continue;
                const int r = residue8(src[i]);
                if (resmask & (1 << r)) continue;
                int cnt = 0;
                for (int j = 0; j < n; ++j)
                    if (!used[j] && residue8(src[j]) == r) ++cnt;
                if (cnt > bestcnt) { bestcnt = cnt; pick = i; }
            }
            if (pick < 0)   // fallback: distinct impossible, take any unused
                for (int i = 0; i < n && pick < 0; ++i) if (!used[i]) pick = i;
            used[pick] = true;
            resmask |= (1 << residue8(src[pick]));
            dst[g * 4 + s] = src[pick];
        }
    }
}

constexpr OffTabs make_tabs() {
    OffTabs t{};
    int ta[36] = {}; int tb[48] = {};
    int na = 0, nb = 0, ne = 0;
    for (int dz = -2; dz <= 2; ++dz)
        for (int dy = -2; dy <= 2; ++dy)
            for (int dx = -2; dx <= 2; ++dx) {
                const int r2 = dz*dz + dy*dy + dx*dx;
                const int off = dz * PS + dy * RS + dx;
                if (r2 <= 4)      ta[na++] = off;
                else if (r2 <= 6) tb[nb++] = off;
                else              t.e[ne++] = off;
            }
    while (na < 36) ta[na++] = 0;   // self-pads: exactly zero force
    permute_groups(ta, 36, t.a);
    permute_groups(tb, 48, t.b);
    return t;
}
__constant__ OffTabs g_tabs = make_tabs();

// ---- bf16 pack/unpack (velocities vy,vz; RNE) -------------------------------
__device__ __forceinline__ unsigned bf16_rne(float f) {
    unsigned u = __float_as_uint(f);
    u += 0x7fffu + ((u >> 16) & 1u);
    return u >> 16;
}
__device__ __forceinline__ unsigned packvv(float vy, float vz) {
    return bf16_rne(vy) | (bf16_rne(vz) << 16);
}
__device__ __forceinline__ float unpk_lo(unsigned w) { return __uint_as_float(w << 16); }
__device__ __forceinline__ float unpk_hi(unsigned w) { return __uint_as_float(w & 0xffff0000u); }

// ---- pair force from preloaded q/w (single-transcendental: rsq) -------------
// rsd = 1/sqrt(sq+1e-20); dist = sq*rsd; rcd == rsd (valid since real contacts
// have dist >= 0.6; self-pair: sq=0 -> dist=0, all force terms * ddx=0 -> 0).
// contact gate on sq<4 (== dist<2, but independent of the rsq result).
__device__ __forceinline__ void pair_qw(
    const float4 q, const unsigned w,
    float px, float py, float pz, float vx, float vy, float vz,
    float& fx, float& fy, float& fz)
{
    const float ddx = px - q.x, ddy = py - q.y, ddz = pz - q.z;
    const float sq  = fmaf(ddx, ddx, fmaf(ddy, ddy, fmaf(ddz, ddz, 1e-20f)));
    const float rsd = __builtin_amdgcn_rsqf(sq);
    const float dist = sq * rsd;
    const float vn = (fmaf(vx - q.w, ddx, fmaf(vy - unpk_lo(w), ddy, (vz - unpk_hi(w)) * ddz))) * rsd;
    float coef = fmaf(KN_F, dist - 2.0f, ETA_F * vn) * rsd;
    coef = (sq < 4.0f) ? coef : 0.0f;
    fx = fmaf(coef, ddx, fx);
    fy = fmaf(coef, ddy, fy);
    fz = fmaf(coef, ddz, fz);
}

__device__ __forceinline__ void pair_full(
    const float4* __restrict__ lsp, const unsigned* __restrict__ lsv, int n,
    float px, float py, float pz, float vx, float vy, float vz,
    float& fx, float& fy, float& fz)
{
    pair_qw(lsp[n], lsv[n], px, py, pz, vx, vy, vz, fx, fy, fz);
}

// ---- the kernel -------------------------------------------------------------
// Launch-bounds note (measured): (NT,6) -> 40 VGPR + ~5MB scratch spill, yet
// FASTEST (61us dispatch / 148.4us bench, round 3). Attempts to "fix" the
// spill (bare bounds 3-wide: 67us; (NT,4) 60 VGPR no-spill: 67us; dual
// accumulators: 66us) all regressed or were null — the spilled codegen's
// schedule wins. This is the measured session optimum, resubmitted exactly.
__global__ __launch_bounds__(NT, 6) void dem_tile(
    const float* __restrict__ X, const float* __restrict__ Y, const float* __restrict__ Z,
    const float* __restrict__ VX, const float* __restrict__ VY, const float* __restrict__ VZ,
    float* __restrict__ out)
{
    __shared__ float4 lsp[SLOTS];          // x,y,z,vx  f32   37888 B (res overlays later)
    __shared__ unsigned lsv[SLOTS];        // vy,vz bf16-pair  9472 B
    __shared__ unsigned short plist[NT];
    __shared__ int loff[128];              // 36 tierA + 48 tierB + 44 exc
    __shared__ unsigned int pcnt;
    __shared__ int nreloc;
    __shared__ int relocidx[8];
    __shared__ float relocval[8][7];

    const int tid = threadIdx.x;

    // XCD-aware swizzle: xcd = blockIdx%8 picks a 16-cell-thick z-slab;
    // loc walks x (4) fastest, then y (32), then z-within-slab (4).
    const unsigned raw = blockIdx.x;
    const unsigned xcd = raw & 7, loc = raw >> 3;
    const int bx = (int)((loc & 3) * TBX);
    const int by = (int)(((loc >> 2) & 31) * TBY);
    const int bz = (int)((xcd * 4 + (loc >> 7)) * TBZ);

    if (tid == 0) { pcnt = 0; nreloc = 0; }
    if (tid < 36) loff[tid] = g_tabs.a[tid];
    else if (tid < 84) loff[tid] = g_tabs.b[tid - 36];
    else if (tid < 128) loff[tid] = g_tabs.e[tid - 84];

    // ---- staging: one halo cell per thread-iteration --------------------------
    // 6 coalesced scalar loads per cell -> one conflict-free ds_write_b128 (lsp)
    // + one b32 (lsv). Wraps handled uniformly; pad slot (x==36) never touched.
    {
        const int bx2 = bx - HALO, by2 = by - HALO, bz2 = bz - HALO;
        #pragma unroll
        for (int it = 0; it < 5; ++it) {
            const int u = tid + it * NT;
            if (it < 4 || u < NHALO) {
                const int r  = (int)((unsigned)u / 36u);   // row 0..63 (magic-mul)
                const int xl = u - r * 36;                 // 0..35
                const int hz = r >> 3, hy = r & 7;
                const int gz = (bz2 + hz) & DMSK;
                const int gy = (by2 + hy) & DMSK;
                const int gx = (bx2 + xl) & DMSK;
                const int g  = (gz << 14) | (gy << 7) | gx;
                const int slot = hz * PS + hy * RS + xl;
                lsp[slot] = make_float4(X[g], Y[g], Z[g], VX[g]);
                lsv[slot] = packvv(VY[g], VZ[g]);
            }
        }
    }

    __syncthreads();   // staging done, pcnt/nreloc init visible

    // ---- own cell, compaction -------------------------------------------------
    const int tx = tid & 31, ty = (tid >> 5) & 3, tz = tid >> 7;
    const int lcc = (tz + HALO) * PS + (ty + HALO) * RS + (tx + HALO);
    const float4 qo = lsp[lcc];
    // occupied <=> stored x != 0 (occupied cells have x >= 0.8; empty exact 0)
    const bool occ = (qo.x != 0.0f);

    {
        const unsigned long long bmask = __ballot(occ);
        const int lane = tid & 63;
        const unsigned int prefix = (unsigned int)__popcll(bmask & ((1ull << lane) - 1ull));
        unsigned int base = 0;
        if (lane == 0) base = atomicAdd(&pcnt, (unsigned int)__popcll(bmask));
        base = __shfl(base, 0, 64);
        if (occ) plist[base + prefix] = (unsigned short)tid;
    }

    // NOTE: empty cells need no integration at all — their state is exactly
    // zero (mask factor in the reference zeroes the update; round(0)==0 ->
    // both cell indices invalid -> dump slot). Their outputs are written as
    // zeros in the res phase; relocation INTO them is handled by the fixups.

    __syncthreads();   // plist complete

    // ---- force phase: 4 lanes per particle ------------------------------------
    const int n = (int)pcnt;
    const int grp = tid >> 2, sub = tid & 3;
    float fa[4], fb[4];
    int fcell[4] = { -1, -1, -1, -1 };

    // per-sub-lane offsets are particle-invariant: hoist into registers
    int offA[9], offB[12];
    #pragma unroll
    for (int t = 0; t < 9; ++t)  offA[t] = loff[t * 4 + sub];
    #pragma unroll
    for (int t = 0; t < 12; ++t) offB[t] = loff[36 + t * 4 + sub];

    #pragma unroll
    for (int pp = 0; pp < 4; ++pp) {       // compile-time bound -> static fa/fb/fcell
        const int i = pp * 128 + grp;
        if (i >= n) break;
        const int p  = plist[i];
        const int px_ = p & 31, py_ = (p >> 5) & 3, pz_ = p >> 7;
        const int lc = (pz_ + HALO) * PS + (py_ + HALO) * RS + (px_ + HALO);
        const int cpg = ((bz + pz_) * DSZ + (by + py_)) * DSZ + (bx + px_);

        const float4 qc = lsp[lc];
        const unsigned wc = lsv[lc];
        const float px = qc.x, py = qc.y, pz = qc.z;
        const float vx = qc.w, vy = unpk_lo(wc), vz = unpk_hi(wc);
        float fx = 0.f, fy = 0.f, fz = 0.f;

        // tier A: real contacts — full compute; loads hoisted per chunk of 3
        #pragma unroll
        for (int c = 0; c < 3; ++c) {
            const int n0 = lc + offA[c * 3 + 0];
            const int n1 = lc + offA[c * 3 + 1];
            const int n2 = lc + offA[c * 3 + 2];
            const float4  q0 = lsp[n0], q1 = lsp[n1], q2 = lsp[n2];
            const unsigned w0 = lsv[n0], w1 = lsv[n1], w2 = lsv[n2];
            pair_qw(q0, w0, px, py, pz, vx, vy, vz, fx, fy, fz);
            pair_qw(q1, w1, px, py, pz, vx, vy, vz, fx, fy, fz);
            pair_qw(q2, w2, px, py, pz, vx, vy, vz, fx, fy, fz);
        }

        // tier B: contact needs near-extreme jitter — batch 6 position reads +
        // sq tests ahead; rare tails are execz-skipped
        #pragma unroll
        for (int c = 0; c < 2; ++c) {
            int nn[6]; float4 qb[6];
            #pragma unroll
            for (int t = 0; t < 6; ++t) {
                nn[t] = lc + offB[c * 6 + t];
                qb[t] = lsp[nn[t]];
            }
            #pragma unroll
            for (int t = 0; t < 6; ++t) {
                const float ddx = px - qb[t].x, ddy = py - qb[t].y, ddz = pz - qb[t].z;
                const float sq = fmaf(ddx, ddx, fmaf(ddy, ddy, fmaf(ddz, ddz, 1e-20f)));
                if (sq < 4.0f) {
                    const float rsd = __builtin_amdgcn_rsqf(sq);
                    const float dist = sq * rsd;
                    const unsigned w = lsv[nn[t]];
                    const float vn = (fmaf(vx - qb[t].w, ddx, fmaf(vy - unpk_lo(w), ddy, (vz - unpk_hi(w)) * ddz))) * rsd;
                    const float coef = fmaf(KN_F, dist - 2.0f, ETA_F * vn) * rsd;
                    fx = fmaf(coef, ddx, fx);
                    fy = fmaf(coef, ddy, fy);
                    fz = fmaf(coef, ddz, fz);
                }
            }
        }

        // empty neighbors sit at the origin: contribute iff |pos|^2 < 4
        // (the (1,1,1)-corner cell) -> run the excluded 44 offsets there.
        const float sqo = px*px + py*py + pz*pz;
        if (sqo < 4.0f) {
            for (int t = sub; t < 44; t += 4)
                pair_full(lsp, lsv, lc + loff[84 + t], px, py, pz, vx, vy, vz, fx, fy, fz);
        }

        fx += __shfl_xor(fx, 1); fy += __shfl_xor(fy, 1); fz += __shfl_xor(fz, 1);
        fx += __shfl_xor(fx, 2); fy += __shfl_xor(fy, 2); fz += __shfl_xor(fz, 2);

        // boundary forces (mask == 1 here)
        const float bl = (px != 0.0f && px < 1.0f)  ? 1.0f : 0.0f;
        const float br = (px > 126.0f)              ? 1.0f : 0.0f;
        const float bb = (py != 0.0f && py < 1.0f)  ? 1.0f : 0.0f;
        const float bt = (py > 126.0f)              ? 1.0f : 0.0f;
        const float bf = (pz != 0.0f && pz < 1.0f)  ? 1.0f : 0.0f;
        const float bk = (pz > 126.0f)              ? 1.0f : 0.0f;
        const float fxb = KN_F * bl * (1.0f - px) - KN_F * br * (px - 126.0f) - ETA_F * vx * (bl + br);
        const float fyb = KN_F * bb * (1.0f - py) - KN_F * bt * (py - 126.0f) - ETA_F * vy * (bb + bt);
        const float fzb = KN_F * bf * (1.0f - pz) - KN_F * bk * (pz - 126.0f) - ETA_F * vz * (bf + bk);

        const float vxn = vx + DT_F * (-fx + fxb);
        const float vyn = vy + DT_F * (-9.8f - fy + fyb);
        const float vzn = vz + DT_F * (-fz + fzb);
        const float xn = px + DT_F * vxn;
        const float yn = py + DT_F * vyn;
        const float zn = pz + DT_F * vzn;

        const int cx0 = (int)rintf(px), cy0 = (int)rintf(py), cz0 = (int)rintf(pz);
        const int cx1 = (int)rintf(xn), cy1 = (int)rintf(yn), cz1 = (int)rintf(zn);
        const int lo = (cx0 && cy0 && cz0) ? ((cz0 * DSZ + cy0) * DSZ + cx0) : D3;
        const int ln = (cx1 && cy1 && cz1) ? ((cz1 * DSZ + cy1) * DSZ + cx1) : D3;

        const bool zeroed = (lo == cpg) && (ln != cpg);
        const float mk = (ln == cpg) ? 1.0f : (zeroed ? 0.0f : 1.0f);
        const float o0 = zeroed ? 0.f : xn,  o1 = zeroed ? 0.f : yn,  o2 = zeroed ? 0.f : zn;
        const float o3 = zeroed ? 0.f : vxn, o4 = zeroed ? 0.f : vyn, o5 = zeroed ? 0.f : vzn;

        fcell[pp] = p;
        fa[pp] = (sub == 0) ? o0 : (sub == 1) ? o1 : (sub == 2) ? o2 : o3;
        fb[pp] = (sub == 0) ? o4 : (sub == 1) ? o5 : mk;

        if (sub == 0) {   // rare relocation: queue direct fixups
            if (lo != cpg && lo < D3) {
                int s = atomicAdd(&nreloc, 1);
                if (s < 8) { relocidx[s] = lo; for (int f = 0; f < 7; ++f) relocval[s][f] = 0.f; }
            }
            if (ln != cpg && ln < D3) {
                int s = atomicAdd(&nreloc, 1);
                if (s < 8) {
                    relocidx[s] = ln;
                    relocval[s][0] = xn;  relocval[s][1] = yn;  relocval[s][2] = zn;
                    relocval[s][3] = vxn; relocval[s][4] = vyn; relocval[s][5] = vzn;
                    relocval[s][6] = 1.f;
                }
            }
        }
    }

    __syncthreads();   // all lsp/lsv force reads complete -> safe to overlay res

    // ---- result staging (res overlays lsp; stride 520 spreads sub-lane banks) --
    float* res = (float*)lsp;              // res[f*RES_S + cell], 14560 B
    if (!occ) {
        #pragma unroll
        for (int f = 0; f < 7; ++f) res[f * RES_S + tid] = 0.0f;
    }
    #pragma unroll
    for (int pp = 0; pp < 4; ++pp) {
        if (fcell[pp] >= 0) {
            res[sub * RES_S + fcell[pp]] = fa[pp];
            if (sub < 3) res[(sub + 4) * RES_S + fcell[pp]] = fb[pp];
        }
    }

    __syncthreads();   // res complete

    // ---- fully-coalesced writeback: 7 fields x 128 dwordx4 --------------------
    for (int u = tid; u < 896; u += NT) {
        const int f = u >> 7, j = u & 127;
        const int cell = 4 * j;
        const int wtx = cell & 31, wty = (cell >> 5) & 3, wtz = cell >> 7;
        const float4 v = *(const float4*)(res + f * RES_S + cell);
        *(float4*)(out + f * D3 + ((bz + wtz) * DSZ + (by + wty)) * DSZ + bx + wtx) = v;
    }

    // ---- rare relocation fixups (never triggers at DT=1e-4) -------------------
    __syncthreads();
    const int nr = nreloc < 8 ? nreloc : 8;
    if (tid < nr) {
        const int idx = relocidx[tid];
        #pragma unroll
        for (int f = 0; f < 7; ++f) out[idx + f * D3] = relocval[tid][f];
    }
}

extern "C" void kernel_launch(void* const* d_in, const int* in_sizes, int n_in,
                              void* d_out, int out_size, void* d_ws, size_t ws_size,
                              hipStream_t stream)
{
    const float* X  = (const float*)d_in[0];
    const float* Y  = (const float*)d_in[1];
    const float* Z  = (const float*)d_in[2];
    const float* VX = (const float*)d_in[3];
    const float* VY = (const float*)d_in[4];
    const float* VZ = (const float*)d_in[5];
    float* out = (float*)d_out;

    dem_tile<<<(D3 / (TBX * TBY * TBZ)), NT, 0, stream>>>(X, Y, Z, VX, VY, VZ, out);
}